// Round 9
// baseline (124.192 us; speedup 1.0000x reference)
//
#include <hip/hip_runtime.h>
#include <stdint.h>

typedef float    f32x4  __attribute__((ext_vector_type(4)));
typedef __bf16   bf16x8 __attribute__((ext_vector_type(8)));
typedef short    s16x8  __attribute__((ext_vector_type(8)));
typedef int      i32x4  __attribute__((ext_vector_type(4)));
typedef unsigned short u16x4 __attribute__((ext_vector_type(4)));

#define DEVINL __device__ __forceinline__

DEVINL unsigned short f2bf(float f) {
  unsigned u = __builtin_bit_cast(unsigned, f);
  return (unsigned short)((u + 0x7fffu + ((u >> 16) & 1u)) >> 16);
}

DEVINL f32x4 mfma16(bf16x8 a, bf16x8 b, f32x4 c) {
  return __builtin_amdgcn_mfma_f32_16x16x32_bf16(a, b, c, 0, 0, 0);
}

DEVINL bf16x8 lds_frag(const unsigned char* p) {
  return __builtin_bit_cast(bf16x8, *(const s16x8*)p);
}

template <int CTRL>
DEVINL float dppf(float x) {
  int xi = __builtin_bit_cast(int, x);
  return __builtin_bit_cast(float, __builtin_amdgcn_update_dpp(xi, xi, CTRL, 0xF, 0xF, true));
}
DEVINL float redmax16(float v) {
  v = fmaxf(v, dppf<0xB1>(v));
  v = fmaxf(v, dppf<0x4E>(v));
  v = fmaxf(v, dppf<0x141>(v));
  v = fmaxf(v, dppf<0x140>(v));
  return v;
}

// ---------------- prep: convert the 4 weight matrices to bf16 ----------------
__global__ __launch_bounds__(256) void prep_w_kernel(
    const float* __restrict__ wq, const float* __restrict__ wk,
    const float* __restrict__ wv, const float* __restrict__ wp,
    unsigned short* __restrict__ wbf) {
  int id = blockIdx.x * 256 + threadIdx.x;
  int m = id >> 12;
  const float* src = (m == 0) ? wq : (m == 1) ? wk : (m == 2) ? wv : wp;
  f32x4 v = ((const f32x4*)src)[id & 4095];
  u16x4 o;
  o[0] = f2bf(v[0]); o[1] = f2bf(v[1]); o[2] = f2bf(v[2]); o[3] = f2bf(v[3]);
  ((u16x4*)wbf)[id] = o;
}

// ---------------- QKV, split 3-way: grid 384 = {Q,K,V} x 128 s-tiles --------
__global__ __launch_bounds__(256) void qkv_kernel(
    const float* __restrict__ x, const float* __restrict__ wav,
    const unsigned short* __restrict__ wbf,
    const float* __restrict__ bq, const float* __restrict__ bk, const float* __restrict__ bv,
    unsigned short* __restrict__ Qb, unsigned short* __restrict__ Kb,
    unsigned short* __restrict__ Vt) {
  __shared__ __align__(16) unsigned char sm[32768];
  const int tid = threadIdx.x;
  const int g = blockIdx.x >> 7;
  const int s0 = (blockIdx.x & 127) * 64;
  const float* srcm = (g == 0) ? x : wav;

  {
    const int c = tid >> 1, half = tid & 1;
    const float* xs = srcm + c * 8192 + s0 + half * 32;
#pragma unroll
    for (int i = 0; i < 8; ++i) {
      f32x4 vx = *(const f32x4*)(xs + i * 4);
#pragma unroll
      for (int j = 0; j < 4; ++j) {
        int s = half * 32 + i * 4 + j;
        int off = (c * 2) ^ ((s & 7) << 4);
        *(unsigned short*)(sm + s * 256 + off) = f2bf(vx[j]);
      }
    }
  }
  __syncthreads();

  const int w = tid >> 6, l = tid & 63, lr = l & 15, lh = l >> 4;
  const int arow = w * 16 + lr;
  const int aswz = (lr & 7) << 4;

  const unsigned char* asrc = sm + arow * 256;
  const unsigned char* wsrc = (const unsigned char*)wbf + g * 32768;
  f32x4 acc[8];
#pragma unroll
  for (int jt = 0; jt < 8; ++jt) acc[jt] = (f32x4){0.f, 0.f, 0.f, 0.f};
#pragma unroll
  for (int ks = 0; ks < 4; ++ks) {
    bf16x8 a = lds_frag(asrc + ((ks * 64 + lh * 16) ^ aswz));
#pragma unroll
    for (int jt = 0; jt < 8; ++jt) {
      bf16x8 bb = __builtin_bit_cast(
          bf16x8, *(const s16x8*)(wsrc + (jt * 16 + lr) * 256 + ks * 64 + lh * 16));
      acc[jt] = mfma16(a, bb, acc[jt]);
    }
  }
  if (g < 2) {
    const float* bias = g ? bk : bq;
    unsigned short* outp = g ? Kb : Qb;
#pragma unroll
    for (int jt = 0; jt < 8; ++jt) {
      float bb = bias[jt * 16 + lr];
#pragma unroll
      for (int r = 0; r < 4; ++r) {
        int row = s0 + w * 16 + lh * 4 + r;
        outp[row * 128 + jt * 16 + lr] = f2bf(acc[jt][r] + bb);
      }
    }
  } else {
    unsigned char* sm2 = sm + 16384;
#pragma unroll
    for (int jt = 0; jt < 8; ++jt) {
      float bb = bv[jt * 16 + lr];
#pragma unroll
      for (int r = 0; r < 4; ++r) {
        int jj = jt * 16 + lr;
        int sl = w * 16 + lh * 4 + r;
        *(unsigned short*)(sm2 + jj * 128 + ((sl * 2) ^ ((jj & 7) << 4))) =
            f2bf(acc[jt][r] + bb);
      }
    }
    __syncthreads();
#pragma unroll
    for (int g2 = 0; g2 < 4; ++g2) {
      int jj = w * 32 + g2 * 8 + (l >> 3);
      s16x8 row = *(const s16x8*)(sm2 + jj * 128 + (((l & 7) * 16) ^ ((jj & 7) << 4)));
      *(s16x8*)(Vt + jj * 8192 + s0 + (l & 7) * 8) = row;
    }
  }
}

// ---------------- flash attention, split-KV, KVBLK=128 ----------------------
// grid = 256*S blocks; bid = sp*256 + hq;  h = hq&1, q-tile = hq>>1.
// NIT iterations of 128 keys.  LDS: K/P shared @0 (16KB: K [128 key][128B],
// then P [64 q][256B] over it), V @16384 (16KB: [64 d][256B]).  32KB total.
// l_ computed by MFMA with an all-ones B operand (replaces redsum).
__global__ __launch_bounds__(256) void attn_kernel(
    const unsigned short* __restrict__ Qb, const unsigned short* __restrict__ Kb,
    const unsigned short* __restrict__ Vt, float* __restrict__ Opart,
    float* __restrict__ Ml, float* __restrict__ Ll, int NIT) {
  __shared__ __align__(16) unsigned char sm[32768];
  const int tid = threadIdx.x;
  const int bid = blockIdx.x;
  const int hq = bid & 255, sp = bid >> 8;
  const int h = hq & 1, q0 = (hq >> 1) * 64;
  const int t0 = sp * NIT;  // in 128-key tiles
  const int w = tid >> 6, l = tid & 63, lr = l & 15, lh = l >> 4;
  const int lswz = (lr & 7) << 4;

  bf16x8 qf[2];
#pragma unroll
  for (int ks = 0; ks < 2; ++ks)
    qf[ks] = __builtin_bit_cast(
        bf16x8, *(const s16x8*)(Qb + (q0 + w * 16 + lr) * 128 + h * 64 + ks * 32 + lh * 8));

  const s16x8 ones_i = {0x3F80, 0x3F80, 0x3F80, 0x3F80, 0x3F80, 0x3F80, 0x3F80, 0x3F80};
  const bf16x8 onesf = __builtin_bit_cast(bf16x8, ones_i);

  f32x4 acc[4];
  float m_[4], l_[4];
#pragma unroll
  for (int i = 0; i < 4; ++i) { acc[i] = (f32x4){0.f,0.f,0.f,0.f}; m_[i] = -1e30f; l_[i] = 0.f; }

  // staging geometry: 1024 chunks of 16B each for K and for V
  int srow[4], soff[4], kldsoff[4], vrow[4], voff[4], vldsoff[4];
#pragma unroll
  for (int i = 0; i < 4; ++i) {
    int ch = tid + i * 256;
    srow[i] = ch >> 3;            // key row 0..127
    soff[i] = (ch & 7) * 8;       // d offset (ushort units)
    kldsoff[i] = srow[i] * 128 + ((soff[i] * 2) ^ ((srow[i] & 7) << 4));
    vrow[i] = ch >> 4;            // d row 0..63
    voff[i] = (ch & 15) * 8;      // key offset (ushort units)
    vldsoff[i] = 16384 + vrow[i] * 256 + ((voff[i] * 2) ^ ((vrow[i] & 7) << 4));
  }

  {  // prologue: stage tile t0
#pragma unroll
    for (int i = 0; i < 4; ++i) {
      i32x4 kv = *(const i32x4*)(Kb + (size_t)(t0 * 128 + srow[i]) * 128 + h * 64 + soff[i]);
      i32x4 vv = *(const i32x4*)(Vt + (size_t)(h * 64 + vrow[i]) * 8192 + t0 * 128 + voff[i]);
      *(i32x4*)(sm + kldsoff[i]) = kv;
      *(i32x4*)(sm + vldsoff[i]) = vv;
    }
  }
  __syncthreads();

  const float sc = 0.18033688011112042f;  // 1/sqrt(64) * log2(e)

  for (int tt = 0; tt < NIT; ++tt) {
    i32x4 nk[4], nv[4];
    if (tt < NIT - 1) {  // register prefetch of next 128-key tile
#pragma unroll
      for (int i = 0; i < 4; ++i) {
        nk[i] = *(const i32x4*)(Kb + (size_t)((t0 + tt + 1) * 128 + srow[i]) * 128 + h * 64 + soff[i]);
        nv[i] = *(const i32x4*)(Vt + (size_t)(h * 64 + vrow[i]) * 8192 + (t0 + tt + 1) * 128 + voff[i]);
      }
    }
    const unsigned char* kp = sm;          // K tile, later P
    const unsigned char* vb = sm + 16384;  // V tile

    // QK^T: 128 keys
    f32x4 s8[8];
#pragma unroll
    for (int nt = 0; nt < 8; ++nt) s8[nt] = (f32x4){0.f,0.f,0.f,0.f};
#pragma unroll
    for (int ks = 0; ks < 2; ++ks) {
#pragma unroll
      for (int nt = 0; nt < 8; ++nt) {
        bf16x8 kf = lds_frag(kp + (nt * 16 + lr) * 128 + ((ks * 64 + lh * 16) ^ lswz));
        s8[nt] = mfma16(qf[ks], kf, s8[nt]);
      }
    }

    // online softmax: one reduction pass per 128 keys; sum via MFMA later
#pragma unroll
    for (int r = 0; r < 4; ++r) {
      float mx = s8[0][r];
#pragma unroll
      for (int nt = 1; nt < 8; ++nt) mx = fmaxf(mx, s8[nt][r]);
      mx = redmax16(mx) * sc;
      float mn = fmaxf(m_[r], mx);
      float al = __builtin_amdgcn_exp2f(m_[r] - mn);
      m_[r] = mn;
      l_[r] *= al;
#pragma unroll
      for (int nt = 0; nt < 8; ++nt)
        s8[nt][r] = __builtin_amdgcn_exp2f(fmaf(s8[nt][r], sc, -mn));
#pragma unroll
      for (int ct = 0; ct < 4; ++ct) acc[ct][r] *= al;
    }

    __syncthreads();  // all K reads done -> safe to overwrite K region with P

    // P -> bf16 -> LDS over K region: P[q][key], row stride 256B, swizzled
    const int qrow = w * 16 + lh * 4;
#pragma unroll
    for (int r = 0; r < 4; r += 2) {
      int qa = qrow + r, qb2 = qrow + r + 1;
      unsigned char* rowa = sm + qa * 256;
      unsigned char* rowb = sm + qb2 * 256;
      int swza = (qa & 7) << 4, swzb = (qb2 & 7) << 4;
#pragma unroll
      for (int nt = 0; nt < 8; ++nt) {
        unsigned u;
        asm("v_cvt_pk_bf16_f32 %0, %1, %2" : "=v"(u) : "v"(s8[nt][r]), "v"(s8[nt][r + 1]));
        int koff = nt * 32 + lr * 2;
        *(unsigned short*)(rowa + (koff ^ swza)) = (unsigned short)u;
        *(unsigned short*)(rowb + (koff ^ swzb)) = (unsigned short)(u >> 16);
      }
    }
    asm volatile("s_waitcnt lgkmcnt(0)" ::: "memory");
    __builtin_amdgcn_sched_barrier(0);

    // PV over 128 keys + l via ones-MFMA (pa rows are per-wave private)
    bf16x8 pa[4];
#pragma unroll
    for (int ks = 0; ks < 4; ++ks)
      pa[ks] = lds_frag(kp + (w * 16 + lr) * 256 + ((ks * 64 + lh * 16) ^ lswz));
    f32x4 lt4 = (f32x4){0.f,0.f,0.f,0.f};
#pragma unroll
    for (int ks = 0; ks < 4; ++ks) {
      lt4 = mfma16(pa[ks], onesf, lt4);
#pragma unroll
      for (int ct = 0; ct < 4; ++ct) {
        bf16x8 vf = lds_frag(vb + (ct * 16 + lr) * 256 + ((ks * 64 + lh * 16) ^ lswz));
        acc[ct] = mfma16(pa[ks], vf, acc[ct]);
      }
    }
#pragma unroll
    for (int r = 0; r < 4; ++r) l_[r] += lt4[r];

    __syncthreads();  // P/V reads done -> safe to restage
    if (tt < NIT - 1) {
#pragma unroll
      for (int i = 0; i < 4; ++i) {
        *(i32x4*)(sm + kldsoff[i]) = nk[i];
        *(i32x4*)(sm + vldsoff[i]) = nv[i];
      }
    }
    __syncthreads();
  }

  // epilogue: write unnormalized partials (f32) + m,l
  float* op = Opart + (size_t)bid * 4096;
#pragma unroll
  for (int ct = 0; ct < 4; ++ct) {
#pragma unroll
    for (int r = 0; r < 4; ++r) {
      int q = w * 16 + lh * 4 + r;
      op[q * 64 + ct * 16 + lr] = acc[ct][r];
    }
  }
  if (lr == 0) {
#pragma unroll
    for (int r = 0; r < 4; ++r) {
      int q = w * 16 + lh * 4 + r;
      Ml[bid * 64 + q] = m_[r];
      Ll[bid * 64 + q] = l_[r];
    }
  }
}

// ---------------- combine v3: coalesced merge of S partials ------------------
__global__ __launch_bounds__(256) void combine_kernel(
    const float* __restrict__ Opart, const float* __restrict__ Ml,
    const float* __restrict__ Ll, unsigned short* __restrict__ Ot, int S) {
  __shared__ float wgt_s[8][32];
  __shared__ float rinv_s[32];
  __shared__ unsigned short lt[64][34];
  const int bid = blockIdx.x;
  const int hq = bid >> 1, half = bid & 1;
  const int h = hq & 1, q0 = (hq >> 1) * 64;
  const int t = threadIdx.x;

  if (t < 32) {
    int qg = half * 32 + t;
    float m8[8];
    float M = -1e30f;
    for (int sp = 0; sp < S; ++sp) {
      m8[sp] = Ml[(size_t)(sp * 256 + hq) * 64 + qg];
      M = fmaxf(M, m8[sp]);
    }
    float L = 0.f;
    for (int sp = 0; sp < S; ++sp) {
      float wv = __builtin_amdgcn_exp2f(m8[sp] - M);
      wgt_s[sp][t] = wv;
      L += Ll[(size_t)(sp * 256 + hq) * 64 + qg] * wv;
    }
    rinv_s[t] = 1.0f / L;
  }
  __syncthreads();

  const int q = t >> 3;
  const int dc = t & 7;
  const int qg = half * 32 + q;
  f32x4 o0 = (f32x4){0.f,0.f,0.f,0.f}, o1 = (f32x4){0.f,0.f,0.f,0.f};
  for (int sp = 0; sp < S; ++sp) {
    const f32x4* src =
        (const f32x4*)(Opart + (size_t)(sp * 256 + hq) * 4096 + qg * 64 + dc * 8);
    float wv = wgt_s[sp][q];
    o0 += src[0] * wv;
    o1 += src[1] * wv;
  }
  float rinv = rinv_s[q];
#pragma unroll
  for (int j = 0; j < 4; ++j) lt[dc * 8 + j][q] = f2bf(o0[j] * rinv);
#pragma unroll
  for (int j = 0; j < 4; ++j) lt[dc * 8 + 4 + j][q] = f2bf(o1[j] * rinv);
  __syncthreads();

  const int d = t >> 2, q8 = (t & 3) * 8;
  unsigned short tmp[8];
#pragma unroll
  for (int j = 0; j < 8; ++j) tmp[j] = lt[d][q8 + j];
  *(s16x8*)(Ot + (size_t)(h * 64 + d) * 8192 + q0 + half * 32 + q8) = *(s16x8*)tmp;
}

// ---------------- proj: out[(c,hp)][wq] = Ot[(c,hp)][wp] Wp^T + bp (f32 out) ---
__global__ __launch_bounds__(256) void proj_kernel(
    const unsigned short* __restrict__ Ot, const unsigned short* __restrict__ wbf,
    const float* __restrict__ bp, float* __restrict__ out) {
  __shared__ __align__(16) unsigned char sm[16384];
  const int tid = threadIdx.x;
  const int r0 = blockIdx.x * 64;
#pragma unroll
  for (int i = 0; i < 4; ++i) {
    int chk = tid + 256 * i;
    i32x4 v = *(const i32x4*)(Ot + r0 * 128 + chk * 8);
    int row = chk >> 4, off = (chk & 15) * 16;
    *(i32x4*)(sm + row * 256 + (off ^ ((row & 7) << 4))) = v;
  }
  __syncthreads();
  const int w = tid >> 6, l = tid & 63, lr = l & 15, lh = l >> 4;
  f32x4 acc[8];
#pragma unroll
  for (int jt = 0; jt < 8; ++jt) acc[jt] = (f32x4){0.f, 0.f, 0.f, 0.f};
  const unsigned char* wsrc = (const unsigned char*)wbf + 3 * 32768;
#pragma unroll
  for (int ks = 0; ks < 4; ++ks) {
    bf16x8 a = lds_frag(sm + (w * 16 + lr) * 256 + ((ks * 64 + lh * 16) ^ ((lr & 7) << 4)));
#pragma unroll
    for (int jt = 0; jt < 8; ++jt) {
      bf16x8 bb = __builtin_bit_cast(
          bf16x8, *(const s16x8*)(wsrc + (jt * 16 + lr) * 256 + ks * 64 + lh * 16));
      acc[jt] = mfma16(a, bb, acc[jt]);
    }
  }
#pragma unroll
  for (int jt = 0; jt < 8; ++jt) {
    float bb = bp[jt * 16 + lr];
#pragma unroll
    for (int r = 0; r < 4; ++r)
      out[(r0 + w * 16 + lh * 4 + r) * 128 + jt * 16 + lr] = acc[jt][r] + bb;
  }
}

extern "C" void kernel_launch(void* const* d_in, const int* in_sizes, int n_in,
                              void* d_out, int out_size, void* d_ws, size_t ws_size,
                              hipStream_t stream) {
  const float* x   = (const float*)d_in[0];
  const float* wav = (const float*)d_in[1];
  const float* Wq  = (const float*)d_in[2];
  const float* bq  = (const float*)d_in[3];
  const float* Wk  = (const float*)d_in[4];
  const float* bk  = (const float*)d_in[5];
  const float* Wv  = (const float*)d_in[6];
  const float* bv  = (const float*)d_in[7];
  const float* Wp  = (const float*)d_in[8];
  const float* bp  = (const float*)d_in[9];
  (void)in_sizes; (void)n_in; (void)out_size;

  unsigned char* ws = (unsigned char*)d_ws;
  unsigned short* Qb  = (unsigned short*)(ws);                 // [8192][128] bf16, 2MB
  unsigned short* Kb  = (unsigned short*)(ws + 2097152);       // [8192][128]
  unsigned short* Vt  = (unsigned short*)(ws + 4194304);       // [128][8192]
  unsigned short* Ot  = (unsigned short*)(ws + 6291456);       // [128][8192]
  unsigned short* Wbf = (unsigned short*)(ws + 8388608);       // 4x[128][128] bf16 (128KB)

  // split-KV factor from workspace budget: per-S bytes = 4MB Opart + 128KB m/l
  const size_t pbase = 8519680;
  int S = 8;
  while (S > 1 && pbase + (size_t)S * 4325376 > ws_size) S >>= 1;
  float* Opart = (float*)(ws + pbase);
  float* Ml    = (float*)(ws + pbase + (size_t)S * 4194304);
  float* Ll    = (float*)(ws + pbase + (size_t)S * 4194304 + (size_t)S * 65536);
  const int NIT = 64 / S;  // 128-key tiles per block

  prep_w_kernel<<<64, 256, 0, stream>>>(Wq, Wk, Wv, Wp, Wbf);
  qkv_kernel<<<384, 256, 0, stream>>>(x, wav, Wbf, bq, bk, bv, Qb, Kb, Vt);
  attn_kernel<<<256 * S, 256, 0, stream>>>(Qb, Kb, Vt, Opart, Ml, Ll, NIT);
  combine_kernel<<<512, 256, 0, stream>>>(Opart, Ml, Ll, Ot, S);
  proj_kernel<<<128, 256, 0, stream>>>(Ot, Wbf, bp, (float*)d_out);
}

// Round 10
// 121.932 us; speedup vs baseline: 1.0185x; 1.0185x over previous
//
#include <hip/hip_runtime.h>
#include <stdint.h>

typedef float    f32x4  __attribute__((ext_vector_type(4)));
typedef __bf16   bf16x8 __attribute__((ext_vector_type(8)));
typedef short    s16x8  __attribute__((ext_vector_type(8)));
typedef int      i32x4  __attribute__((ext_vector_type(4)));
typedef unsigned short u16x4 __attribute__((ext_vector_type(4)));

#define DEVINL __device__ __forceinline__

DEVINL unsigned short f2bf(float f) {
  unsigned u = __builtin_bit_cast(unsigned, f);
  return (unsigned short)((u + 0x7fffu + ((u >> 16) & 1u)) >> 16);
}

DEVINL f32x4 mfma16(bf16x8 a, bf16x8 b, f32x4 c) {
  return __builtin_amdgcn_mfma_f32_16x16x32_bf16(a, b, c, 0, 0, 0);
}

DEVINL bf16x8 lds_frag(const unsigned char* p) {
  return __builtin_bit_cast(bf16x8, *(const s16x8*)p);
}

template <int CTRL>
DEVINL float dppf(float x) {
  int xi = __builtin_bit_cast(int, x);
  return __builtin_bit_cast(float, __builtin_amdgcn_update_dpp(xi, xi, CTRL, 0xF, 0xF, true));
}
DEVINL float redmax16(float v) {
  v = fmaxf(v, dppf<0xB1>(v));
  v = fmaxf(v, dppf<0x4E>(v));
  v = fmaxf(v, dppf<0x141>(v));
  v = fmaxf(v, dppf<0x140>(v));
  return v;
}

// ---------------- prep: convert the 4 weight matrices to bf16 ----------------
__global__ __launch_bounds__(256) void prep_w_kernel(
    const float* __restrict__ wq, const float* __restrict__ wk,
    const float* __restrict__ wv, const float* __restrict__ wp,
    unsigned short* __restrict__ wbf) {
  int id = blockIdx.x * 256 + threadIdx.x;
  int m = id >> 12;
  const float* src = (m == 0) ? wq : (m == 1) ? wk : (m == 2) ? wv : wp;
  f32x4 v = ((const f32x4*)src)[id & 4095];
  u16x4 o;
  o[0] = f2bf(v[0]); o[1] = f2bf(v[1]); o[2] = f2bf(v[2]); o[3] = f2bf(v[3]);
  ((u16x4*)wbf)[id] = o;
}

// ---------------- QKV, split 3-way: grid 384 = {Q,K,V} x 128 s-tiles --------
__global__ __launch_bounds__(256) void qkv_kernel(
    const float* __restrict__ x, const float* __restrict__ wav,
    const unsigned short* __restrict__ wbf,
    const float* __restrict__ bq, const float* __restrict__ bk, const float* __restrict__ bv,
    unsigned short* __restrict__ Qb, unsigned short* __restrict__ Kb,
    unsigned short* __restrict__ Vt) {
  __shared__ __align__(16) unsigned char sm[32768];
  const int tid = threadIdx.x;
  const int g = blockIdx.x >> 7;
  const int s0 = (blockIdx.x & 127) * 64;
  const float* srcm = (g == 0) ? x : wav;

  {
    const int c = tid >> 1, half = tid & 1;
    const float* xs = srcm + c * 8192 + s0 + half * 32;
#pragma unroll
    for (int i = 0; i < 8; ++i) {
      f32x4 vx = *(const f32x4*)(xs + i * 4);
#pragma unroll
      for (int j = 0; j < 4; ++j) {
        int s = half * 32 + i * 4 + j;
        int off = (c * 2) ^ ((s & 7) << 4);
        *(unsigned short*)(sm + s * 256 + off) = f2bf(vx[j]);
      }
    }
  }
  __syncthreads();

  const int w = tid >> 6, l = tid & 63, lr = l & 15, lh = l >> 4;
  const int arow = w * 16 + lr;
  const int aswz = (lr & 7) << 4;

  const unsigned char* asrc = sm + arow * 256;
  const unsigned char* wsrc = (const unsigned char*)wbf + g * 32768;
  f32x4 acc[8];
#pragma unroll
  for (int jt = 0; jt < 8; ++jt) acc[jt] = (f32x4){0.f, 0.f, 0.f, 0.f};
#pragma unroll
  for (int ks = 0; ks < 4; ++ks) {
    bf16x8 a = lds_frag(asrc + ((ks * 64 + lh * 16) ^ aswz));
#pragma unroll
    for (int jt = 0; jt < 8; ++jt) {
      bf16x8 bb = __builtin_bit_cast(
          bf16x8, *(const s16x8*)(wsrc + (jt * 16 + lr) * 256 + ks * 64 + lh * 16));
      acc[jt] = mfma16(a, bb, acc[jt]);
    }
  }
  if (g < 2) {
    const float* bias = g ? bk : bq;
    unsigned short* outp = g ? Kb : Qb;
#pragma unroll
    for (int jt = 0; jt < 8; ++jt) {
      float bb = bias[jt * 16 + lr];
#pragma unroll
      for (int r = 0; r < 4; ++r) {
        int row = s0 + w * 16 + lh * 4 + r;
        outp[row * 128 + jt * 16 + lr] = f2bf(acc[jt][r] + bb);
      }
    }
  } else {
    unsigned char* sm2 = sm + 16384;
#pragma unroll
    for (int jt = 0; jt < 8; ++jt) {
      float bb = bv[jt * 16 + lr];
#pragma unroll
      for (int r = 0; r < 4; ++r) {
        int jj = jt * 16 + lr;
        int sl = w * 16 + lh * 4 + r;
        *(unsigned short*)(sm2 + jj * 128 + ((sl * 2) ^ ((jj & 7) << 4))) =
            f2bf(acc[jt][r] + bb);
      }
    }
    __syncthreads();
#pragma unroll
    for (int g2 = 0; g2 < 4; ++g2) {
      int jj = w * 32 + g2 * 8 + (l >> 3);
      s16x8 row = *(const s16x8*)(sm2 + jj * 128 + (((l & 7) * 16) ^ ((jj & 7) << 4)));
      *(s16x8*)(Vt + jj * 8192 + s0 + (l & 7) * 8) = row;
    }
  }
}

// ---------------- flash attention, split-KV, KVBLK=128, panel LDS -----------
// grid = 256*S; bid = sp*256 + hq; h = hq&1, q-tile = hq>>1; NIT 128-key iters.
// LDS (all rows 128B, XOR ((row&7)<<4) — the measured-zero-conflict form):
//   K panels @0/@8192   [64 key][128B]  (keys 0..63 / 64..127); P overwrites.
//   V panels @16384/@24576 [64 d][128B] (keys 0..63 / 64..127).
__global__ __launch_bounds__(256) void attn_kernel(
    const unsigned short* __restrict__ Qb, const unsigned short* __restrict__ Kb,
    const unsigned short* __restrict__ Vt, float* __restrict__ Opart,
    float* __restrict__ Ml, float* __restrict__ Ll, int NIT) {
  __shared__ __align__(16) unsigned char sm[32768];
  const int tid = threadIdx.x;
  const int bid = blockIdx.x;
  const int hq = bid & 255, sp = bid >> 8;
  const int h = hq & 1, q0 = (hq >> 1) * 64;
  const int t0 = sp * NIT;  // in 128-key tiles
  const int w = tid >> 6, l = tid & 63, lr = l & 15, lh = l >> 4;
  const int lswz = (lr & 7) << 4;

  bf16x8 qf[2];
#pragma unroll
  for (int ks = 0; ks < 2; ++ks)
    qf[ks] = __builtin_bit_cast(
        bf16x8, *(const s16x8*)(Qb + (q0 + w * 16 + lr) * 128 + h * 64 + ks * 32 + lh * 8));

  const s16x8 ones_i = {0x3F80, 0x3F80, 0x3F80, 0x3F80, 0x3F80, 0x3F80, 0x3F80, 0x3F80};
  const bf16x8 onesf = __builtin_bit_cast(bf16x8, ones_i);

  f32x4 acc[4];
  float m_[4], l_[4];
#pragma unroll
  for (int i = 0; i < 4; ++i) { acc[i] = (f32x4){0.f,0.f,0.f,0.f}; m_[i] = -1e30f; l_[i] = 0.f; }

  // staging geometry: 1024 chunks of 16B each for K and V, panel-split
  int kglob[4], kldsoff[4], vglob[4], vldsoff[4];
#pragma unroll
  for (int i = 0; i < 4; ++i) {
    int ch = tid + i * 256;
    int key = ch >> 3, slot = ch & 7;        // K: key 0..127, 8 d-slots
    int kr = key & 63;
    kldsoff[i] = (key >> 6) * 8192 + kr * 128 + ((slot * 16) ^ ((kr & 7) << 4));
    kglob[i] = key * 128 + h * 64 + slot * 8;  // + t*128*128
    int d = ch >> 4, kslot = ch & 15;        // V: d 0..63, 16 key-slots of 8
    vldsoff[i] = 16384 + (kslot >> 3) * 8192 + d * 128 +
                 (((kslot & 7) * 16) ^ ((d & 7) << 4));
    vglob[i] = (h * 64 + d) * 8192 + kslot * 8;  // + t*128
  }

  {  // prologue: stage tile t0
#pragma unroll
    for (int i = 0; i < 4; ++i) {
      i32x4 kv = *(const i32x4*)(Kb + (size_t)t0 * 16384 + kglob[i]);
      i32x4 vv = *(const i32x4*)(Vt + (size_t)t0 * 128 + vglob[i]);
      *(i32x4*)(sm + kldsoff[i]) = kv;
      *(i32x4*)(sm + vldsoff[i]) = vv;
    }
  }
  __syncthreads();

  const float sc = 0.18033688011112042f;  // 1/sqrt(64) * log2(e)

  for (int tt = 0; tt < NIT; ++tt) {
    i32x4 nk[4], nv[4];
    if (tt < NIT - 1) {  // register prefetch of next 128-key tile
#pragma unroll
      for (int i = 0; i < 4; ++i) {
        nk[i] = *(const i32x4*)(Kb + (size_t)(t0 + tt + 1) * 16384 + kglob[i]);
        nv[i] = *(const i32x4*)(Vt + (size_t)(t0 + tt + 1) * 128 + vglob[i]);
      }
    }

    // QK^T: 128 keys; K panel = nt>>2, row (nt&3)*16+lr  (row&7 == lr&7)
    f32x4 s8[8];
#pragma unroll
    for (int nt = 0; nt < 8; ++nt) s8[nt] = (f32x4){0.f,0.f,0.f,0.f};
#pragma unroll
    for (int ks = 0; ks < 2; ++ks) {
#pragma unroll
      for (int nt = 0; nt < 8; ++nt) {
        const unsigned char* kf_p = sm + (nt >> 2) * 8192 + ((nt & 3) * 16 + lr) * 128 +
                                    ((ks * 64 + lh * 16) ^ lswz);
        s8[nt] = mfma16(qf[ks], lds_frag(kf_p), s8[nt]);
      }
    }

    // online softmax: one reduction pass per 128 keys; l via ones-MFMA later
#pragma unroll
    for (int r = 0; r < 4; ++r) {
      float mx = s8[0][r];
#pragma unroll
      for (int nt = 1; nt < 8; ++nt) mx = fmaxf(mx, s8[nt][r]);
      mx = redmax16(mx) * sc;
      float mn = fmaxf(m_[r], mx);
      float al = __builtin_amdgcn_exp2f(m_[r] - mn);
      m_[r] = mn;
      l_[r] *= al;
#pragma unroll
      for (int nt = 0; nt < 8; ++nt)
        s8[nt][r] = __builtin_amdgcn_exp2f(fmaf(s8[nt][r], sc, -mn));
#pragma unroll
      for (int ct = 0; ct < 4; ++ct) acc[ct][r] *= al;
    }

    __syncthreads();  // K reads done -> safe to overwrite K panels with P

    // P -> bf16 -> K panels: panel nt>>2, row q, byte ((nt&3)*32 + lr*2) ^ swz
    const int qrow = w * 16 + lh * 4;
#pragma unroll
    for (int r = 0; r < 4; r += 2) {
      int qa = qrow + r, qb2 = qrow + r + 1;
      int swza = (qa & 7) << 4, swzb = (qb2 & 7) << 4;
#pragma unroll
      for (int nt = 0; nt < 8; ++nt) {
        unsigned u;
        asm("v_cvt_pk_bf16_f32 %0, %1, %2" : "=v"(u) : "v"(s8[nt][r]), "v"(s8[nt][r + 1]));
        unsigned char* pan = sm + (nt >> 2) * 8192;
        int koff = (nt & 3) * 32 + lr * 2;
        *(unsigned short*)(pan + qa * 128 + (koff ^ swza)) = (unsigned short)u;
        *(unsigned short*)(pan + qb2 * 128 + (koff ^ swzb)) = (unsigned short)(u >> 16);
      }
    }
    asm volatile("s_waitcnt lgkmcnt(0)" ::: "memory");
    __builtin_amdgcn_sched_barrier(0);

    // PV over 128 keys + l via ones-MFMA. ks-step covers keys ks*32+lh*8..+7:
    // panel = ks>>1, in-panel offset ((ks&1)*64 + lh*16) ^ swz.
    bf16x8 pa[4];
#pragma unroll
    for (int ks = 0; ks < 4; ++ks)
      pa[ks] = lds_frag(sm + (ks >> 1) * 8192 + (w * 16 + lr) * 128 +
                        (((ks & 1) * 64 + lh * 16) ^ lswz));
    f32x4 lt4 = (f32x4){0.f,0.f,0.f,0.f};
#pragma unroll
    for (int ks = 0; ks < 4; ++ks) {
      lt4 = mfma16(pa[ks], onesf, lt4);
      const unsigned char* vpan = sm + 16384 + (ks >> 1) * 8192;
#pragma unroll
      for (int ct = 0; ct < 4; ++ct) {
        bf16x8 vf = lds_frag(vpan + (ct * 16 + lr) * 128 +
                             (((ks & 1) * 64 + lh * 16) ^ lswz));
        acc[ct] = mfma16(pa[ks], vf, acc[ct]);
      }
    }
#pragma unroll
    for (int r = 0; r < 4; ++r) l_[r] += lt4[r];

    __syncthreads();  // P/V reads done -> safe to restage
    if (tt < NIT - 1) {
#pragma unroll
      for (int i = 0; i < 4; ++i) {
        *(i32x4*)(sm + kldsoff[i]) = nk[i];
        *(i32x4*)(sm + vldsoff[i]) = nv[i];
      }
    }
    __syncthreads();
  }

  // epilogue: write unnormalized partials (f32) + m,l
  float* op = Opart + (size_t)bid * 4096;
#pragma unroll
  for (int ct = 0; ct < 4; ++ct) {
#pragma unroll
    for (int r = 0; r < 4; ++r) {
      int q = w * 16 + lh * 4 + r;
      op[q * 64 + ct * 16 + lr] = acc[ct][r];
    }
  }
  if (lr == 0) {
#pragma unroll
    for (int r = 0; r < 4; ++r) {
      int q = w * 16 + lh * 4 + r;
      Ml[bid * 64 + q] = m_[r];
      Ll[bid * 64 + q] = l_[r];
    }
  }
}

// ---------------- combine v3: coalesced merge of S partials ------------------
__global__ __launch_bounds__(256) void combine_kernel(
    const float* __restrict__ Opart, const float* __restrict__ Ml,
    const float* __restrict__ Ll, unsigned short* __restrict__ Ot, int S) {
  __shared__ float wgt_s[8][32];
  __shared__ float rinv_s[32];
  __shared__ unsigned short lt[64][34];
  const int bid = blockIdx.x;
  const int hq = bid >> 1, half = bid & 1;
  const int h = hq & 1, q0 = (hq >> 1) * 64;
  const int t = threadIdx.x;

  if (t < 32) {
    int qg = half * 32 + t;
    float m8[8];
    float M = -1e30f;
    for (int sp = 0; sp < S; ++sp) {
      m8[sp] = Ml[(size_t)(sp * 256 + hq) * 64 + qg];
      M = fmaxf(M, m8[sp]);
    }
    float L = 0.f;
    for (int sp = 0; sp < S; ++sp) {
      float wv = __builtin_amdgcn_exp2f(m8[sp] - M);
      wgt_s[sp][t] = wv;
      L += Ll[(size_t)(sp * 256 + hq) * 64 + qg] * wv;
    }
    rinv_s[t] = 1.0f / L;
  }
  __syncthreads();

  const int q = t >> 3;
  const int dc = t & 7;
  const int qg = half * 32 + q;
  f32x4 o0 = (f32x4){0.f,0.f,0.f,0.f}, o1 = (f32x4){0.f,0.f,0.f,0.f};
  for (int sp = 0; sp < S; ++sp) {
    const f32x4* src =
        (const f32x4*)(Opart + (size_t)(sp * 256 + hq) * 4096 + qg * 64 + dc * 8);
    float wv = wgt_s[sp][q];
    o0 += src[0] * wv;
    o1 += src[1] * wv;
  }
  float rinv = rinv_s[q];
#pragma unroll
  for (int j = 0; j < 4; ++j) lt[dc * 8 + j][q] = f2bf(o0[j] * rinv);
#pragma unroll
  for (int j = 0; j < 4; ++j) lt[dc * 8 + 4 + j][q] = f2bf(o1[j] * rinv);
  __syncthreads();

  const int d = t >> 2, q8 = (t & 3) * 8;
  unsigned short tmp[8];
#pragma unroll
  for (int j = 0; j < 8; ++j) tmp[j] = lt[d][q8 + j];
  *(s16x8*)(Ot + (size_t)(h * 64 + d) * 8192 + q0 + half * 32 + q8) = *(s16x8*)tmp;
}

// ---------------- proj: out[(c,hp)][wq] = Ot[(c,hp)][wp] Wp^T + bp (f32 out) ---
__global__ __launch_bounds__(256) void proj_kernel(
    const unsigned short* __restrict__ Ot, const unsigned short* __restrict__ wbf,
    const float* __restrict__ bp, float* __restrict__ out) {
  __shared__ __align__(16) unsigned char sm[16384];
  const int tid = threadIdx.x;
  const int r0 = blockIdx.x * 64;
#pragma unroll
  for (int i = 0; i < 4; ++i) {
    int chk = tid + 256 * i;
    i32x4 v = *(const i32x4*)(Ot + r0 * 128 + chk * 8);
    int row = chk >> 4, off = (chk & 15) * 16;
    *(i32x4*)(sm + row * 256 + (off ^ ((row & 7) << 4))) = v;
  }
  __syncthreads();
  const int w = tid >> 6, l = tid & 63, lr = l & 15, lh = l >> 4;
  f32x4 acc[8];
#pragma unroll
  for (int jt = 0; jt < 8; ++jt) acc[jt] = (f32x4){0.f, 0.f, 0.f, 0.f};
  const unsigned char* wsrc = (const unsigned char*)wbf + 3 * 32768;
#pragma unroll
  for (int ks = 0; ks < 4; ++ks) {
    bf16x8 a = lds_frag(sm + (w * 16 + lr) * 256 + ((ks * 64 + lh * 16) ^ ((lr & 7) << 4)));
#pragma unroll
    for (int jt = 0; jt < 8; ++jt) {
      bf16x8 bb = __builtin_bit_cast(
          bf16x8, *(const s16x8*)(wsrc + (jt * 16 + lr) * 256 + ks * 64 + lh * 16));
      acc[jt] = mfma16(a, bb, acc[jt]);
    }
  }
#pragma unroll
  for (int jt = 0; jt < 8; ++jt) {
    float bb = bp[jt * 16 + lr];
#pragma unroll
    for (int r = 0; r < 4; ++r)
      out[(r0 + w * 16 + lh * 4 + r) * 128 + jt * 16 + lr] = acc[jt][r] + bb;
  }
}

extern "C" void kernel_launch(void* const* d_in, const int* in_sizes, int n_in,
                              void* d_out, int out_size, void* d_ws, size_t ws_size,
                              hipStream_t stream) {
  const float* x   = (const float*)d_in[0];
  const float* wav = (const float*)d_in[1];
  const float* Wq  = (const float*)d_in[2];
  const float* bq  = (const float*)d_in[3];
  const float* Wk  = (const float*)d_in[4];
  const float* bk  = (const float*)d_in[5];
  const float* Wv  = (const float*)d_in[6];
  const float* bv  = (const float*)d_in[7];
  const float* Wp  = (const float*)d_in[8];
  const float* bp  = (const float*)d_in[9];
  (void)in_sizes; (void)n_in; (void)out_size;

  unsigned char* ws = (unsigned char*)d_ws;
  unsigned short* Qb  = (unsigned short*)(ws);                 // [8192][128] bf16, 2MB
  unsigned short* Kb  = (unsigned short*)(ws + 2097152);       // [8192][128]
  unsigned short* Vt  = (unsigned short*)(ws + 4194304);       // [128][8192]
  unsigned short* Ot  = (unsigned short*)(ws + 6291456);       // [128][8192]
  unsigned short* Wbf = (unsigned short*)(ws + 8388608);       // 4x[128][128] bf16 (128KB)

  // split-KV factor from workspace budget: per-S bytes = 4MB Opart + 128KB m/l
  const size_t pbase = 8519680;
  int S = 8;
  while (S > 1 && pbase + (size_t)S * 4325376 > ws_size) S >>= 1;
  float* Opart = (float*)(ws + pbase);
  float* Ml    = (float*)(ws + pbase + (size_t)S * 4194304);
  float* Ll    = (float*)(ws + pbase + (size_t)S * 4194304 + (size_t)S * 65536);
  const int NIT = 64 / S;  // 128-key tiles per block

  prep_w_kernel<<<64, 256, 0, stream>>>(Wq, Wk, Wv, Wp, Wbf);
  qkv_kernel<<<384, 256, 0, stream>>>(x, wav, Wbf, bq, bk, bv, Qb, Kb, Vt);
  attn_kernel<<<256 * S, 256, 0, stream>>>(Qb, Kb, Vt, Opart, Ml, Ll, NIT);
  combine_kernel<<<512, 256, 0, stream>>>(Opart, Ml, Ll, Ot, S);
  proj_kernel<<<128, 256, 0, stream>>>(Ot, Wbf, bp, (float*)d_out);
}